// Round 3
// baseline (436.918 us; speedup 1.0000x reference)
//
#include <hip/hip_runtime.h>
#include <cstdint>
#include <cstddef>

typedef unsigned short ushort;
typedef __attribute__((ext_vector_type(8))) short short8;    // 8 x bf16 (4 VGPRs)
typedef __attribute__((ext_vector_type(16))) float f32x16;   // 32x32 accumulator

__device__ __forceinline__ float bf2f(ushort u) {
  union { unsigned u; float f; } c; c.u = ((unsigned)u) << 16; return c.f;
}
__device__ __forceinline__ ushort f2bf(float f) {
  union { float f; unsigned u; } c; c.f = f;
  unsigned u = c.u;
  return (ushort)((u + 0x7fffu + ((u >> 16) & 1u)) >> 16);   // RNE
}

#define G2L(g, l) __builtin_amdgcn_global_load_lds( \
    (const __attribute__((address_space(1))) void*)(g), \
    (__attribute__((address_space(3))) void*)(l), 16, 0, 0)

#define BARRIER() do { asm volatile("" ::: "memory"); __builtin_amdgcn_s_barrier(); asm volatile("" ::: "memory"); } while (0)
#define LGKM0()   do { asm volatile("s_waitcnt lgkmcnt(0)" ::: "memory"); __builtin_amdgcn_sched_barrier(0); } while (0)

// ---------------- MFMA GEMM: C[M,N] = A[M,K] . B[N,K]^T (+bias) ----------------
// 256xBN tile (BN=256 or 128), BK=64, **4 waves (256 thr)**, wave-tile 128x128
// (BN=256; MF=NF=4) or 64x128 (BN=128; MF=2,NF=4).
// Rationale (R2 post-mortem): the LDS unit serializes ~192 ds_read_b128/K-tile
// at 8 waves x (128+64)-row wave tiles -> ~3.5k cyc vs 2.0k MFMA wall. 4 waves
// at 128x128 need only 128 reads/K-tile -> LDS wall ~= MFMA wall.
// Pipeline per K-tile t (R1 protocol, proven):
//   vmcnt(LPS) + barrier       : tile t landed (t+1's LPS loads stay in flight)
//   frag-read h+1 ahead of MFMA h (double-buffered slots, static idx)
//   lgkmcnt(0) + barrier       : buf[cur] fully read block-wide (WAR gate)
//   STAGE(buf[cur], t+2)       : depth-2 prefetch, never drains vmcnt to 0
// LDS layout: [row][k-chunk], chunk = 8 elems = 16B, row stride 128B.
// Swizzle: global chunk q of row r lives at LDS chunk (q + r) & 7; staging
// pre-rotates the per-lane GLOBAL source (G2L dest stays linear).
// MODE 0: bias fp32, write bf16 / MODE 1,2: write bf16 / MODE 3: bias, fp32 split @512.
struct MArgs {
  const ushort* A; int lda; long asz;
  const ushort* B; int ldb; long bsz;
  void* C; int ldc; long csz;
  int K;
  const float* bias;
  float* C2;
};

template<int MODE, int BN>
__launch_bounds__(256, 1)
__global__ void mfma_gemm(MArgs g) {
  constexpr int BM = 256;
  constexpr int WN = (BN == 256) ? 2 : 1;   // waves along N
  constexpr int WM = 4 / WN;                // waves along M
  constexpr int WMSZ = BM / WM;             // 128 or 64
  constexpr int WNSZ = BN / WN;             // 128
  constexpr int MF = WMSZ / 32;             // 4 or 2
  constexpr int NF = WNSZ / 32;             // 4
  constexpr int NAG = BM / 32;              // A staging groups of 32 rows = 8
  constexpr int NBG = BN / 32;              // 8 or 4
  constexpr int LPS = NAG + NBG;            // G2L per thread per K-tile (16 or 12)

  __shared__ __attribute__((aligned(16))) ushort As[2][BM * 64];
  __shared__ __attribute__((aligned(16))) ushort Bs[2][BN * 64];

  const int tid = threadIdx.x;
  const int lane = tid & 63;
  const int wave = tid >> 6;
  const int z = blockIdx.z;

  // XCD-aware swizzle (nwg = 256 in all stages)
  int bx = blockIdx.x, by = blockIdx.y;
  {
    const int gx = gridDim.x;
    const int nwg = gx * gridDim.y;
    int wg = by * gx + bx;
    wg = (wg & 7) * (nwg >> 3) + (wg >> 3);
    bx = wg % gx; by = wg / gx;
  }
  const long m0 = (long)by * BM;
  const long n0 = (long)bx * BN;
  const ushort* Ab = g.A + (long)z * g.asz;
  const ushort* Bb = g.B + (long)z * g.bsz;

  // ---- staging: thread t -> row (t>>3) in each 32-row group, LDS chunk (t&7);
  // global chunk = (ldschunk - row) & 7  (row rotation; row mod 8 == srow mod 8)
  const int srow = tid >> 3;
  const long skel = (long)((((tid & 7) - srow) & 7) * 8);
  const ushort* ga0 = Ab + (m0 + srow) * (long)g.lda + skel;
  const ushort* gb0 = Bb + (n0 + srow) * (long)g.ldb + skel;
  const long astep = 32L * (long)g.lda;
  const long bstep = 32L * (long)g.ldb;

  // ---- fragment read offsets: lane l reads X[r][k = 16h + 8*(l>>5) + j];
  // stored chunk = (2h + (l>>5) + r) & 7
  const int l31 = lane & 31, hb = lane >> 5;
  const int wmi = wave / WN, wni = wave % WN;
  int aoff[MF], arot[MF];
#pragma unroll
  for (int mf = 0; mf < MF; ++mf) {
    const int r = wmi * WMSZ + mf * 32 + l31;
    aoff[mf] = r * 64;
    arot[mf] = (r + hb) & 7;
  }
  int boff[NF], brot[NF];
#pragma unroll
  for (int nf = 0; nf < NF; ++nf) {
    const int r = wni * WNSZ + nf * 32 + l31;
    boff[nf] = r * 64;
    brot[nf] = (r + hb) & 7;
  }

  f32x16 acc[MF][NF];
#pragma unroll
  for (int mf = 0; mf < MF; ++mf)
#pragma unroll
    for (int nf = 0; nf < NF; ++nf)
#pragma unroll
      for (int r = 0; r < 16; ++r) acc[mf][nf][r] = 0.f;

  auto STAGEF = [&](int buf, int t) {
    const long ko = (long)t * 64;
    const ushort* p = ga0 + ko;
    ushort* l = &As[buf][tid * 8];
#pragma unroll
    for (int q = 0; q < NAG; ++q) { G2L(p, l); p += astep; l += 2048; }
    p = gb0 + ko;
    l = &Bs[buf][tid * 8];
#pragma unroll
    for (int q = 0; q < NBG; ++q) { G2L(p, l); p += bstep; l += 2048; }
  };

  STAGEF(0, 0);            // tile 0 -> buf 0
  STAGEF(1, 1);            // tile 1 -> buf 1   (nt >= 3 in all stages)

  const int nt = g.K >> 6;
  int cur = 0;
  for (int t = 0; t < nt; ++t) {
    // RAW gate: tile t complete; tile t+1's LPS loads stay in flight
    if (t + 1 < nt) asm volatile("s_waitcnt vmcnt(%0)" :: "n"(LPS) : "memory");
    else            asm volatile("s_waitcnt vmcnt(0)" ::: "memory");
    BARRIER();

    const ushort* as = &As[cur][0];
    const ushort* bs = &Bs[cur][0];
    short8 av[2][MF], bv[2][NF];

#define READ_S(s, h) do { \
  _Pragma("unroll") for (int mf = 0; mf < MF; ++mf) \
    av[s][mf] = *(const short8*)(as + aoff[mf] + (((2 * (h) + arot[mf]) & 7) << 3)); \
  _Pragma("unroll") for (int nf = 0; nf < NF; ++nf) \
    bv[s][nf] = *(const short8*)(bs + boff[nf] + (((2 * (h) + brot[nf]) & 7) << 3)); \
} while (0)
#define MFMA_S(s) do { \
  _Pragma("unroll") for (int mf = 0; mf < MF; ++mf) \
  _Pragma("unroll") for (int nf = 0; nf < NF; ++nf) \
    acc[mf][nf] = __builtin_amdgcn_mfma_f32_32x32x16_bf16(av[s][mf], bv[s][nf], acc[mf][nf], 0, 0, 0); \
} while (0)

    // software-pipelined frag reads: issue h+1's reads before h's MFMAs
    READ_S(0, 0);
    READ_S(1, 1);
    MFMA_S(0);
    READ_S(0, 2);
    MFMA_S(1);
    READ_S(1, 3);
    MFMA_S(0);
    MFMA_S(1);
#undef READ_S
#undef MFMA_S

    // WAR gate: all reads of buf[cur] complete block-wide before overwrite
    LGKM0();
    BARRIER();
    if (t + 2 < nt) STAGEF(cur, t + 2);
    cur ^= 1;
  }

  // ---- epilogue: C/D map (m74/m101): col=lane&31, row=(reg&3)+8*(reg>>2)+4*(lane>>5)
  const int cc = l31;
  const int rbase = 4 * hb;
  ushort* Cu = (ushort*)g.C + (long)z * g.csz;
  float* Cf = (float*)g.C;
#pragma unroll
  for (int mf = 0; mf < MF; ++mf) {
#pragma unroll
    for (int nf = 0; nf < NF; ++nf) {
      const long col = n0 + wni * WNSZ + nf * 32 + cc;
      float bsv = 0.f;
      if (MODE == 0 || MODE == 3) bsv = g.bias[col];
#pragma unroll
      for (int r = 0; r < 16; ++r) {
        const long row = m0 + wmi * WMSZ + mf * 32 + (r & 3) + 8 * (r >> 2) + rbase;
        float v = acc[mf][nf][r] + bsv;
        if (MODE == 3) {
          float* dst = (col < 512) ? (Cf + row * 512 + col) : (g.C2 + row * 512 + (col - 512));
          *dst = v;
        } else {
          Cu[row * (long)g.ldc + col] = f2bf(v);
        }
      }
    }
  }
}

// ---------------- converts ----------------
__global__ void cvt_x6(const float* x0, const float* x1, const float* x2,
                       const float* x3, const float* x4, const float* x5, ushort* X) {
  const long m = blockIdx.y;
  const int c4 = (blockIdx.x * 256 + threadIdx.x) * 4;  // 0..3071
  const int p = c4 >> 9, d = c4 & 511;
  const float* xp;
  switch (p) {
    case 0: xp = x0; break; case 1: xp = x1; break; case 2: xp = x2; break;
    case 3: xp = x3; break; case 4: xp = x4; break; default: xp = x5; break;
  }
  float4 v = *(const float4*)(xp + m * 512 + d);
  ushort4 o; o.x = f2bf(v.x); o.y = f2bf(v.y); o.z = f2bf(v.z); o.w = f2bf(v.w);
  *(ushort4*)(X + m * 3072 + c4) = o;
}

__device__ __forceinline__ int chunk_map(int c) { return (c == 0) ? 0 : (c == 1) ? 2 : (c == 2) ? 4 : 5; }

__global__ void cvt_w4(const float* W, ushort* Wq4) {
  const long r = blockIdx.y;                       // 0..2047
  const int c4 = (blockIdx.x * 256 + threadIdx.x) * 4;
  const long wr = (long)chunk_map((int)(r >> 9)) * 512 + (r & 511);
  float4 v = *(const float4*)(W + wr * 3072 + c4);
  ushort4 o; o.x = f2bf(v.x); o.y = f2bf(v.y); o.z = f2bf(v.z); o.w = f2bf(v.w);
  *(ushort4*)(Wq4 + r * 3072 + c4) = o;
}

__global__ void cvt_wout(const float* W, ushort* Wo) {
  const long r = blockIdx.y;
  const int c4 = threadIdx.x * 4;
  float4 v = *(const float4*)(W + r * 1024 + c4);
  ushort4 o; o.x = f2bf(v.x); o.y = f2bf(v.y); o.z = f2bf(v.z); o.w = f2bf(v.w);
  *(ushort4*)(Wo + r * 1024 + c4) = o;
}

__global__ void mk_bias4(const float* bqkv, float* b4) {
  const int n = blockIdx.x * 256 + threadIdx.x;    // 0..2047
  b4[n] = bqkv[chunk_map(n >> 9) * 512 + (n & 511)];
}

// ---------------- V transpose: Vt_b[n][k] = QKV[b*2048+k][1024+n] ----------------
__global__ void transpose_v(const ushort* QKV, ushort* Vt) {
  __shared__ ushort t[64][65];
  const int tid = threadIdx.x;
  const int k0 = blockIdx.x * 64, n0 = blockIdx.y * 64, b = blockIdx.z;
  const ushort* src = QKV + (long)b * 2048 * 2048 + 1024;
#pragma unroll
  for (int i = 0; i < 16; ++i) {
    int idx = i * 256 + tid; int r = idx >> 6, c = idx & 63;
    t[r][c] = src[(long)(k0 + r) * 2048 + (n0 + c)];
  }
  __syncthreads();
  ushort* dst = Vt + (long)b * 1024 * 2048;
#pragma unroll
  for (int i = 0; i < 16; ++i) {
    int idx = i * 256 + tid; int r = idx >> 6, c = idx & 63;
    dst[(long)(n0 + r) * 2048 + (k0 + c)] = t[c][r];
  }
}

// ---------------- softmax: lane owns one contiguous 64B chunk (32 elems) ----------------
__launch_bounds__(256)
__global__ void softmax_rows(ushort* S, const int* mask) {
  const int lane = threadIdx.x & 63;
  const int wave = threadIdx.x >> 6;
  const long row = (long)blockIdx.x * 4 + wave;            // 0..8191
  const int* m = mask + (row >> 11) * 2048 + lane * 32;
  ushort* s = S + row * 2048 + lane * 32;
  const float scale = 0.04419417382415922f;                // 512^-0.5

  short8 raw[4];
#pragma unroll
  for (int i = 0; i < 4; ++i) raw[i] = *(const short8*)(s + i * 8);
  int4 mi[8];
#pragma unroll
  for (int i = 0; i < 8; ++i) mi[i] = *(const int4*)(m + i * 4);

  float v[32];
  int mk[32];
#pragma unroll
  for (int i = 0; i < 8; ++i) {
    mk[i * 4 + 0] = mi[i].x; mk[i * 4 + 1] = mi[i].y;
    mk[i * 4 + 2] = mi[i].z; mk[i * 4 + 3] = mi[i].w;
  }
#pragma unroll
  for (int i = 0; i < 32; ++i) v[i] = bf2f((ushort)raw[i >> 3][i & 7]) * scale;

  float mx = -INFINITY;
#pragma unroll
  for (int i = 0; i < 32; ++i) if (!mk[i]) mx = fmaxf(mx, v[i]);
#pragma unroll
  for (int off = 32; off; off >>= 1) mx = fmaxf(mx, __shfl_xor(mx, off));

  float sum = 0.f;
#pragma unroll
  for (int i = 0; i < 32; ++i) {
    float e = mk[i] ? 0.f : __expf(v[i] - mx);
    v[i] = e;
    sum += e;
  }
#pragma unroll
  for (int off = 32; off; off >>= 1) sum += __shfl_xor(sum, off);

  float r = 1.f / sum;
  short8 out[4];
#pragma unroll
  for (int i = 0; i < 32; ++i) out[i >> 3][i & 7] = (short)f2bf(v[i] * r);
#pragma unroll
  for (int i = 0; i < 4; ++i) *(short8*)(s + i * 8) = out[i];
}

// ---------------- launcher ----------------
extern "C" void kernel_launch(void* const* d_in, const int* in_sizes, int n_in,
                              void* d_out, int out_size, void* d_ws, size_t ws_size,
                              hipStream_t stream) {
  const float* qr = (const float*)d_in[0];
  const float* qi = (const float*)d_in[1];
  const float* kr = (const float*)d_in[2];
  const float* ki = (const float*)d_in[3];
  const float* vr = (const float*)d_in[4];
  const float* vi = (const float*)d_in[5];
  const int* pm = (const int*)d_in[6];
  const float* Wqkv = (const float*)d_in[7];
  const float* bqkv = (const float*)d_in[8];
  const float* Wout = (const float*)d_in[9];
  const float* bout = (const float*)d_in[10];
  float* out = (float*)d_out;

  // ws layout (bytes):
  char* base = (char*)d_ws;
  ushort* QKV   = (ushort*)(base);                         // 8192x2048 bf16   33,554,432
  ushort* Wq4   = (ushort*)(base + 33554432);              // 2048x3072 bf16   12,582,912
  ushort* Wo    = (ushort*)(base + 46137344);              // 1024x1024 bf16    2,097,152
  float*  b4    = (float*) (base + 48234496);              // 2048 fp32             8,192
  char*   uni   = base + 48242688;
  ushort* Xbf   = (ushort*)(uni);                          // 8192x3072 bf16   50,331,648 (dies after stage1)
  ushort* Vt    = (ushort*)(uni);                          // 4x1024x2048 bf16 16,777,216
  ushort* S     = (ushort*)(uni + 16777216);               // 4x2048x2048 bf16 33,554,432
  ushort* AO    = (ushort*)(uni + 50331648);               // 8192x1024 bf16   16,777,216
  // total 115,351,552 bytes

  // converts
  cvt_x6<<<dim3(3, 8192), 256, 0, stream>>>(qr, qi, kr, ki, vr, vi, Xbf);
  cvt_w4<<<dim3(3, 2048), 256, 0, stream>>>(Wqkv, Wq4);
  cvt_wout<<<dim3(1, 1024), 256, 0, stream>>>(Wout, Wo);
  mk_bias4<<<8, 256, 0, stream>>>(bqkv, b4);

  // stage 1: QKV = Xbf(8192x3072) . Wq4(2048x3072)^T + b4  -> bf16   [grid 256 = 1 block/CU]
  {
    MArgs a{};
    a.A = Xbf; a.lda = 3072; a.asz = 0;
    a.B = Wq4; a.ldb = 3072; a.bsz = 0;
    a.C = QKV; a.ldc = 2048; a.csz = 0;
    a.K = 3072; a.bias = b4;
    mfma_gemm<0, 256><<<dim3(8, 32, 1), 256, 0, stream>>>(a);
  }

  // V transpose (reads QKV cols 1024..2047)
  transpose_v<<<dim3(32, 16, 4), 256, 0, stream>>>(QKV, Vt);

  // stage 2: S_b = Q_b(2048x512) . K_b(2048x512)^T  -> bf16 (raw scores)  [grid 256]
  {
    MArgs a{};
    a.A = QKV;        a.lda = 2048; a.asz = (long)2048 * 2048;
    a.B = QKV + 512;  a.ldb = 2048; a.bsz = (long)2048 * 2048;
    a.C = S;          a.ldc = 2048; a.csz = (long)2048 * 2048;
    a.K = 512;
    mfma_gemm<1, 256><<<dim3(8, 8, 4), 256, 0, stream>>>(a);
  }

  // stage 3: softmax rows in place (scale + mask + exp + norm)
  softmax_rows<<<2048, 256, 0, stream>>>(S, pm);

  // stage 4: AO_b = P_b(2048x2048) . Vt_b(1024x2048)^T  -> bf16   [BN=128, grid 256]
  {
    MArgs a{};
    a.A = S;  a.lda = 2048; a.asz = (long)2048 * 2048;
    a.B = Vt; a.ldb = 2048; a.bsz = (long)1024 * 2048;
    a.C = AO; a.ldc = 1024; a.csz = (long)2048 * 1024;
    a.K = 2048;
    mfma_gemm<2, 128><<<dim3(8, 8, 4), 256, 0, stream>>>(a);
  }

  // stage 5: out = AO(8192x1024) . Wo(1024x1024)^T + bout -> fp32 split   [BN=128, grid 256]
  {
    MArgs a{};
    a.A = AO; a.lda = 1024; a.asz = 0;
    a.B = Wo; a.ldb = 1024; a.bsz = 0;
    a.C = out; a.ldc = 512; a.csz = 0;
    a.C2 = out + (long)8192 * 512;
    a.K = 1024; a.bias = bout;
    mfma_gemm<3, 128><<<dim3(8, 32, 1), 256, 0, stream>>>(a);
  }
}

// Round 4
// 408.605 us; speedup vs baseline: 1.0693x; 1.0693x over previous
//
#include <hip/hip_runtime.h>
#include <cstdint>
#include <cstddef>

typedef unsigned short ushort;
typedef __attribute__((ext_vector_type(8))) short short8;    // 8 x bf16 (4 VGPRs)
typedef __attribute__((ext_vector_type(16))) float f32x16;   // 32x32 accumulator

__device__ __forceinline__ float bf2f(ushort u) {
  union { unsigned u; float f; } c; c.u = ((unsigned)u) << 16; return c.f;
}
__device__ __forceinline__ ushort f2bf(float f) {
  union { float f; unsigned u; } c; c.f = f;
  unsigned u = c.u;
  return (ushort)((u + 0x7fffu + ((u >> 16) & 1u)) >> 16);   // RNE
}

#define G2L(g, l) __builtin_amdgcn_global_load_lds( \
    (const __attribute__((address_space(1))) void*)(g), \
    (__attribute__((address_space(3))) void*)(l), 16, 0, 0)

#define BARRIER() do { asm volatile("" ::: "memory"); __builtin_amdgcn_s_barrier(); asm volatile("" ::: "memory"); } while (0)
#define LGKM0()   do { asm volatile("s_waitcnt lgkmcnt(0)" ::: "memory"); __builtin_amdgcn_sched_barrier(0); } while (0)

// ---------------- MFMA GEMM: C[M,N] = A[M,K] . B[N,K]^T (+bias) ----------------
// 256xBN tile (BN=256 or 128), BK=64, 8 waves (512 thr), double-buffered LDS.
// R4: m201-style WINDOW schedule. Per K-tile, 4 windows; window h:
//   issue READ_H(h): 6 ds_read_b128 (this window's fragments)
//   issue staging share: w0 = STAGE_A(t+1), w1 = STAGE_B(t+1)  (into buf[c^1],
//     which is read-complete: its reads drained block-wide before tile t began)
//   barrier  -> lgkmcnt(0)+sched_barrier  -> setprio(1) + 8 MFMA + setprio(0) -> barrier
// While MFMAs of window h run, the LDS unit keeps draining the queued reads/writes
// -> LDS unit (the pacer: 192 reads x 16cyc + 64KB writes ~ 3.5k cyc/tile vs MFMA
// 2k) stays continuously busy instead of convoying at one per-tile drain.
// Tile-end: vmcnt(0) (stage(t+1) issued 2-3 windows ago -> retires stall-free,
// loads still spanned 6+ barriers in flight) + barrier gates next tile's reads.
// LDS layout: [row][k-chunk], chunk = 8 elems = 16B, row stride 128B.
// Swizzle: global chunk q of row r lives at LDS chunk (q + r) & 7; staging
// pre-rotates the per-lane GLOBAL source (G2L dest stays linear).
// MODE 0: bias fp32, write bf16 / MODE 1,2: write bf16 / MODE 3: bias, fp32 split @512.
struct MArgs {
  const ushort* A; int lda; long asz;
  const ushort* B; int ldb; long bsz;
  void* C; int ldc; long csz;
  int K;
  const float* bias;
  float* C2;
};

template<int MODE, int BN>
__launch_bounds__(512, 2)
__global__ void mfma_gemm(MArgs g) {
  constexpr int BM = 256;
  constexpr int WN = BN / 64;        // waves along N (4 or 2)
  constexpr int WM = 8 / WN;         // waves along M (2 or 4)
  constexpr int WMSZ = BM / WM;      // per-wave M extent (128 or 64)
  constexpr int MF = WMSZ / 32;      // A frags per wave (4 or 2)
  constexpr int NBG = BN / 64;       // B staging groups (4 or 2)

  __shared__ __attribute__((aligned(16))) ushort As[2][BM * 64];
  __shared__ __attribute__((aligned(16))) ushort Bs[2][BN * 64];

  const int tid = threadIdx.x;
  const int lane = tid & 63;
  const int wave = tid >> 6;
  const int z = blockIdx.z;

  // XCD-aware swizzle (nwg is a multiple of 8 in all stages: 256/64/64/256)
  int bx = blockIdx.x, by = blockIdx.y;
  {
    const int gx = gridDim.x;
    const int nwg = gx * gridDim.y;
    int wg = by * gx + bx;
    wg = (wg & 7) * (nwg >> 3) + (wg >> 3);
    bx = wg % gx; by = wg / gx;
  }
  const long m0 = (long)by * BM;
  const long n0 = (long)bx * BN;
  const ushort* Ab = g.A + (long)z * g.asz;
  const ushort* Bb = g.B + (long)z * g.bsz;

  // ---- staging: thread t -> row (t>>3) in each 64-row group, LDS chunk (t&7);
  // global chunk = (ldschunk - row) & 7  (row rotation)
  const int srow = tid >> 3;
  const long skel = (long)((((tid & 7) - srow) & 7) * 8);
  const ushort* ga[4];
  const ushort* gb[NBG];
#pragma unroll
  for (int q = 0; q < 4; ++q) ga[q] = Ab + (m0 + q * 64 + srow) * (long)g.lda + skel;
#pragma unroll
  for (int q = 0; q < NBG; ++q) gb[q] = Bb + (n0 + q * 64 + srow) * (long)g.ldb + skel;

  // ---- fragment read offsets: lane l reads X[r = base + (l&31)][k = 16h + 8*(l>>5) + j]
  // stored chunk = (2h + (l>>5) + r) & 7
  const int l31 = lane & 31, hb = lane >> 5;
  const int wmi = wave / WN, wni = wave % WN;
  int aoff[MF], arot[MF];
#pragma unroll
  for (int mf = 0; mf < MF; ++mf) {
    const int r = wmi * WMSZ + mf * 32 + l31;
    aoff[mf] = r * 64;
    arot[mf] = (r + hb) & 7;
  }
  int boff[2], brot[2];
#pragma unroll
  for (int nf = 0; nf < 2; ++nf) {
    const int r = wni * 64 + nf * 32 + l31;
    boff[nf] = r * 64;
    brot[nf] = (r + hb) & 7;
  }

  f32x16 acc[MF][2];
#pragma unroll
  for (int mf = 0; mf < MF; ++mf)
#pragma unroll
    for (int nf = 0; nf < 2; ++nf)
#pragma unroll
      for (int r = 0; r < 16; ++r) acc[mf][nf][r] = 0.f;

  auto STAGE_A = [&](int buf, int t) {
    const long ko = (long)t * 64;
#pragma unroll
    for (int q = 0; q < 4; ++q) G2L(ga[q] + ko, &As[buf][q * 4096 + tid * 8]);
  };
  auto STAGE_B = [&](int buf, int t) {
    const long ko = (long)t * 64;
#pragma unroll
    for (int q = 0; q < NBG; ++q) G2L(gb[q] + ko, &Bs[buf][q * 4096 + tid * 8]);
  };

  // prologue: tile 0 only; tile t+1 staged during tile t's windows
  STAGE_A(0, 0); STAGE_B(0, 0);
  asm volatile("s_waitcnt vmcnt(0)" ::: "memory");
  BARRIER();

  const int nt = g.K >> 6;
  for (int t = 0; t < nt; ++t) {
    const int c = t & 1;
    const ushort* as = &As[c][0];
    const ushort* bs = &Bs[c][0];

    // window h: reads -> stage share -> barrier -> lgkm0 -> MFMA -> POST
#define WIN(h, STG, POST) do { \
      short8 avv[MF], bvv[2]; \
      _Pragma("unroll") for (int mf = 0; mf < MF; ++mf) \
        avv[mf] = *(const short8*)(as + aoff[mf] + (((2 * (h) + arot[mf]) & 7) << 3)); \
      _Pragma("unroll") for (int nf = 0; nf < 2; ++nf) \
        bvv[nf] = *(const short8*)(bs + boff[nf] + (((2 * (h) + brot[nf]) & 7) << 3)); \
      STG; \
      BARRIER(); \
      LGKM0(); \
      __builtin_amdgcn_s_setprio(1); \
      _Pragma("unroll") for (int mf = 0; mf < MF; ++mf) \
      _Pragma("unroll") for (int nf = 0; nf < 2; ++nf) \
        acc[mf][nf] = __builtin_amdgcn_mfma_f32_32x32x16_bf16(avv[mf], bvv[nf], acc[mf][nf], 0, 0, 0); \
      __builtin_amdgcn_s_setprio(0); \
      POST; \
    } while (0)

    WIN(0, { if (t + 1 < nt) STAGE_A(c ^ 1, t + 1); }, BARRIER());
    WIN(1, { if (t + 1 < nt) STAGE_B(c ^ 1, t + 1); }, BARRIER());
    WIN(2, {}, BARRIER());
    WIN(3, {}, {
      if (t + 1 < nt) {
        asm volatile("s_waitcnt vmcnt(0)" ::: "memory");  // stage(t+1) retired (issued 2-3 windows ago)
        BARRIER();                                        // gate: next tile's reads safe
      }
    });
#undef WIN
  }

  // ---- epilogue: C/D map (m74/m101): col=lane&31, row=(reg&3)+8*(reg>>2)+4*(lane>>5)
  const int cc = l31;
  const int rbase = 4 * hb;
  ushort* Cu = (ushort*)g.C + (long)z * g.csz;
  float* Cf = (float*)g.C;
#pragma unroll
  for (int mf = 0; mf < MF; ++mf) {
#pragma unroll
    for (int nf = 0; nf < 2; ++nf) {
      const long col = n0 + wni * 64 + nf * 32 + cc;
      float bsv = 0.f;
      if (MODE == 0 || MODE == 3) bsv = g.bias[col];
#pragma unroll
      for (int r = 0; r < 16; ++r) {
        const long row = m0 + wmi * WMSZ + mf * 32 + (r & 3) + 8 * (r >> 2) + rbase;
        float v = acc[mf][nf][r] + bsv;
        if (MODE == 3) {
          float* dst = (col < 512) ? (Cf + row * 512 + col) : (g.C2 + row * 512 + (col - 512));
          *dst = v;
        } else {
          Cu[row * (long)g.ldc + col] = f2bf(v);
        }
      }
    }
  }
}

// ---------------- converts ----------------
__global__ void cvt_x6(const float* x0, const float* x1, const float* x2,
                       const float* x3, const float* x4, const float* x5, ushort* X) {
  const long m = blockIdx.y;
  const int c4 = (blockIdx.x * 256 + threadIdx.x) * 4;  // 0..3071
  const int p = c4 >> 9, d = c4 & 511;
  const float* xp;
  switch (p) {
    case 0: xp = x0; break; case 1: xp = x1; break; case 2: xp = x2; break;
    case 3: xp = x3; break; case 4: xp = x4; break; default: xp = x5; break;
  }
  float4 v = *(const float4*)(xp + m * 512 + d);
  ushort4 o; o.x = f2bf(v.x); o.y = f2bf(v.y); o.z = f2bf(v.z); o.w = f2bf(v.w);
  *(ushort4*)(X + m * 3072 + c4) = o;
}

__device__ __forceinline__ int chunk_map(int c) { return (c == 0) ? 0 : (c == 1) ? 2 : (c == 2) ? 4 : 5; }

__global__ void cvt_w4(const float* W, ushort* Wq4) {
  const long r = blockIdx.y;                       // 0..2047
  const int c4 = (blockIdx.x * 256 + threadIdx.x) * 4;
  const long wr = (long)chunk_map((int)(r >> 9)) * 512 + (r & 511);
  float4 v = *(const float4*)(W + wr * 3072 + c4);
  ushort4 o; o.x = f2bf(v.x); o.y = f2bf(v.y); o.z = f2bf(v.z); o.w = f2bf(v.w);
  *(ushort4*)(Wq4 + r * 3072 + c4) = o;
}

__global__ void cvt_wout(const float* W, ushort* Wo) {
  const long r = blockIdx.y;
  const int c4 = threadIdx.x * 4;
  float4 v = *(const float4*)(W + r * 1024 + c4);
  ushort4 o; o.x = f2bf(v.x); o.y = f2bf(v.y); o.z = f2bf(v.z); o.w = f2bf(v.w);
  *(ushort4*)(Wo + r * 1024 + c4) = o;
}

__global__ void mk_bias4(const float* bqkv, float* b4) {
  const int n = blockIdx.x * 256 + threadIdx.x;    // 0..2047
  b4[n] = bqkv[chunk_map(n >> 9) * 512 + (n & 511)];
}

// ---------------- V transpose: Vt_b[n][k] = QKV[b*2048+k][1024+n] ----------------
__global__ void transpose_v(const ushort* QKV, ushort* Vt) {
  __shared__ ushort t[64][65];
  const int tid = threadIdx.x;
  const int k0 = blockIdx.x * 64, n0 = blockIdx.y * 64, b = blockIdx.z;
  const ushort* src = QKV + (long)b * 2048 * 2048 + 1024;
#pragma unroll
  for (int i = 0; i < 16; ++i) {
    int idx = i * 256 + tid; int r = idx >> 6, c = idx & 63;
    t[r][c] = src[(long)(k0 + r) * 2048 + (n0 + c)];
  }
  __syncthreads();
  ushort* dst = Vt + (long)b * 1024 * 2048;
#pragma unroll
  for (int i = 0; i < 16; ++i) {
    int idx = i * 256 + tid; int r = idx >> 6, c = idx & 63;
    dst[(long)(n0 + r) * 2048 + (k0 + c)] = t[c][r];
  }
}

// ---------------- softmax: lane owns one contiguous 64B chunk (32 elems) ----------------
__launch_bounds__(256)
__global__ void softmax_rows(ushort* S, const int* mask) {
  const int lane = threadIdx.x & 63;
  const int wave = threadIdx.x >> 6;
  const long row = (long)blockIdx.x * 4 + wave;            // 0..8191
  const int* m = mask + (row >> 11) * 2048 + lane * 32;
  ushort* s = S + row * 2048 + lane * 32;
  const float scale = 0.04419417382415922f;                // 512^-0.5

  short8 raw[4];
#pragma unroll
  for (int i = 0; i < 4; ++i) raw[i] = *(const short8*)(s + i * 8);
  int4 mi[8];
#pragma unroll
  for (int i = 0; i < 8; ++i) mi[i] = *(const int4*)(m + i * 4);

  float v[32];
  int mk[32];
#pragma unroll
  for (int i = 0; i < 8; ++i) {
    mk[i * 4 + 0] = mi[i].x; mk[i * 4 + 1] = mi[i].y;
    mk[i * 4 + 2] = mi[i].z; mk[i * 4 + 3] = mi[i].w;
  }
#pragma unroll
  for (int i = 0; i < 32; ++i) v[i] = bf2f((ushort)raw[i >> 3][i & 7]) * scale;

  float mx = -INFINITY;
#pragma unroll
  for (int i = 0; i < 32; ++i) if (!mk[i]) mx = fmaxf(mx, v[i]);
#pragma unroll
  for (int off = 32; off; off >>= 1) mx = fmaxf(mx, __shfl_xor(mx, off));

  float sum = 0.f;
#pragma unroll
  for (int i = 0; i < 32; ++i) {
    float e = mk[i] ? 0.f : __expf(v[i] - mx);
    v[i] = e;
    sum += e;
  }
#pragma unroll
  for (int off = 32; off; off >>= 1) sum += __shfl_xor(sum, off);

  float r = 1.f / sum;
  short8 out[4];
#pragma unroll
  for (int i = 0; i < 32; ++i) out[i >> 3][i & 7] = (short)f2bf(v[i] * r);
#pragma unroll
  for (int i = 0; i < 4; ++i) *(short8*)(s + i * 8) = out[i];
}

// ---------------- launcher ----------------
extern "C" void kernel_launch(void* const* d_in, const int* in_sizes, int n_in,
                              void* d_out, int out_size, void* d_ws, size_t ws_size,
                              hipStream_t stream) {
  const float* qr = (const float*)d_in[0];
  const float* qi = (const float*)d_in[1];
  const float* kr = (const float*)d_in[2];
  const float* ki = (const float*)d_in[3];
  const float* vr = (const float*)d_in[4];
  const float* vi = (const float*)d_in[5];
  const int* pm = (const int*)d_in[6];
  const float* Wqkv = (const float*)d_in[7];
  const float* bqkv = (const float*)d_in[8];
  const float* Wout = (const float*)d_in[9];
  const float* bout = (const float*)d_in[10];
  float* out = (float*)d_out;

  // ws layout (bytes):
  char* base = (char*)d_ws;
  ushort* QKV   = (ushort*)(base);                         // 8192x2048 bf16   33,554,432
  ushort* Wq4   = (ushort*)(base + 33554432);              // 2048x3072 bf16   12,582,912
  ushort* Wo    = (ushort*)(base + 46137344);              // 1024x1024 bf16    2,097,152
  float*  b4    = (float*) (base + 48234496);              // 2048 fp32             8,192
  char*   uni   = base + 48242688;
  ushort* Xbf   = (ushort*)(uni);                          // 8192x3072 bf16   50,331,648 (dies after stage1)
  ushort* Vt    = (ushort*)(uni);                          // 4x1024x2048 bf16 16,777,216
  ushort* S     = (ushort*)(uni + 16777216);               // 4x2048x2048 bf16 33,554,432
  ushort* AO    = (ushort*)(uni + 50331648);               // 8192x1024 bf16   16,777,216
  // total 115,351,552 bytes

  // converts
  cvt_x6<<<dim3(3, 8192), 256, 0, stream>>>(qr, qi, kr, ki, vr, vi, Xbf);
  cvt_w4<<<dim3(3, 2048), 256, 0, stream>>>(Wqkv, Wq4);
  cvt_wout<<<dim3(1, 1024), 256, 0, stream>>>(Wout, Wo);
  mk_bias4<<<8, 256, 0, stream>>>(bqkv, b4);

  // stage 1: QKV = Xbf(8192x3072) . Wq4(2048x3072)^T + b4  -> bf16   [grid 256 = 1 block/CU]
  {
    MArgs a{};
    a.A = Xbf; a.lda = 3072; a.asz = 0;
    a.B = Wq4; a.ldb = 3072; a.bsz = 0;
    a.C = QKV; a.ldc = 2048; a.csz = 0;
    a.K = 3072; a.bias = b4;
    mfma_gemm<0, 256><<<dim3(8, 32, 1), 512, 0, stream>>>(a);
  }

  // V transpose (reads QKV cols 1024..2047)
  transpose_v<<<dim3(32, 16, 4), 256, 0, stream>>>(QKV, Vt);

  // stage 2: S_b = Q_b(2048x512) . K_b(2048x512)^T  -> bf16 (raw scores)  [grid 256]
  {
    MArgs a{};
    a.A = QKV;        a.lda = 2048; a.asz = (long)2048 * 2048;
    a.B = QKV + 512;  a.ldb = 2048; a.bsz = (long)2048 * 2048;
    a.C = S;          a.ldc = 2048; a.csz = (long)2048 * 2048;
    a.K = 512;
    mfma_gemm<1, 256><<<dim3(8, 8, 4), 512, 0, stream>>>(a);
  }

  // stage 3: softmax rows in place (scale + mask + exp + norm)
  softmax_rows<<<2048, 256, 0, stream>>>(S, pm);

  // stage 4: AO_b = P_b(2048x2048) . Vt_b(1024x2048)^T  -> bf16   [BN=128, grid 256]
  {
    MArgs a{};
    a.A = S;  a.lda = 2048; a.asz = (long)2048 * 2048;
    a.B = Vt; a.ldb = 2048; a.bsz = (long)1024 * 2048;
    a.C = AO; a.ldc = 1024; a.csz = (long)2048 * 1024;
    a.K = 2048;
    mfma_gemm<2, 128><<<dim3(8, 8, 4), 512, 0, stream>>>(a);
  }

  // stage 5: out = AO(8192x1024) . Wo(1024x1024)^T + bout -> fp32 split   [BN=128, grid 256]
  {
    MArgs a{};
    a.A = AO; a.lda = 1024; a.asz = 0;
    a.B = Wo; a.ldb = 1024; a.bsz = 0;
    a.C = out; a.ldc = 512; a.csz = 0;
    a.C2 = out + (long)8192 * 512;
    a.K = 1024; a.bias = bout;
    mfma_gemm<3, 128><<<dim3(8, 32, 1), 512, 0, stream>>>(a);
  }
}

// Round 5
// 391.841 us; speedup vs baseline: 1.1150x; 1.0428x over previous
//
#include <hip/hip_runtime.h>
#include <cstdint>
#include <cstddef>

typedef unsigned short ushort;
typedef __attribute__((ext_vector_type(8))) short short8;    // 8 x bf16 (4 VGPRs)
typedef __attribute__((ext_vector_type(16))) float f32x16;   // 32x32 accumulator

__device__ __forceinline__ float bf2f(ushort u) {
  union { unsigned u; float f; } c; c.u = ((unsigned)u) << 16; return c.f;
}
__device__ __forceinline__ ushort f2bf(float f) {
  union { float f; unsigned u; } c; c.f = f;
  unsigned u = c.u;
  return (ushort)((u + 0x7fffu + ((u >> 16) & 1u)) >> 16);   // RNE
}

#define G2L(g, l) __builtin_amdgcn_global_load_lds( \
    (const __attribute__((address_space(1))) void*)(g), \
    (__attribute__((address_space(3))) void*)(l), 16, 0, 0)

#define BARRIER() do { asm volatile("" ::: "memory"); __builtin_amdgcn_s_barrier(); asm volatile("" ::: "memory"); } while (0)
// counted LDS wait: oldest (outstanding-N) DS ops complete (DS returns in order).
// rule 18: sched_barrier(0) after, so MFMAs can't hoist above the wait.
#define LGKMC(N) do { asm volatile("s_waitcnt lgkmcnt(%0)" :: "n"(N) : "memory"); __builtin_amdgcn_sched_barrier(0); } while (0)

__device__ __forceinline__ unsigned ldsoff(const void* p) {
  return (unsigned)(unsigned long long)(__attribute__((address_space(3))) const void*)p;
}

// ---------------- MFMA GEMM: C[M,N] = A[M,K] . B[N,K]^T (+bias) ----------------
// 256xBN tile (BN=256 or 128), BK=64, 8 waves (512 thr), double-buffered LDS.
// R5: COUNTED-LGKM pipeline (the piece R1-R4 all lacked; they drained lgkm to 0
// before every MFMA cluster -> read-drain and MFMA serialized, tile 5520 cyc vs
// LDS wall 3584 / MFMA wall 2068). Inline-asm ds_read_b128 so WE own the hazard:
//   issue h0+h1 (2*RD reads) -> lgkm(RD): h0 landed, h1 in flight
//   MFMA h0   (h1 drains under it)  -> issue h2 -> lgkm(RD)
//   MFMA h1   (h2 drains)           -> issue h3 -> lgkm(RD)
//   MFMA h2   -> lgkm(0) -> BARRIER (block-wide WAR gate on buf[cur])
//   STAGE(t+2 -> cur)  -> MFMA h3 (overlaps G2L issue)
// Tile start: vmcnt(LPS) + barrier = RAW gate (tile t landed, t+1's LPS loads in
// flight; never drained to 0 mid-loop). Depth-2 prefetch throughout.
// LDS layout: [row][k-chunk], chunk = 8 elems = 16B, row stride 128B.
// Swizzle: global chunk q of row r lives at LDS chunk (q + r) & 7; staging
// pre-rotates the per-lane GLOBAL source (G2L dest stays linear).
// MODE 0: bias fp32, write bf16 / MODE 1,2: write bf16 / MODE 3: bias, fp32 split @512.
struct MArgs {
  const ushort* A; int lda; long asz;
  const ushort* B; int ldb; long bsz;
  void* C; int ldc; long csz;
  int K;
  const float* bias;
  float* C2;
};

template<int MODE, int BN>
__launch_bounds__(512, 2)
__global__ void mfma_gemm(MArgs g) {
  constexpr int BM = 256;
  constexpr int WN = BN / 64;        // waves along N (4 or 2)
  constexpr int WM = 8 / WN;         // waves along M (2 or 4)
  constexpr int WMSZ = BM / WM;      // per-wave M extent (128 or 64)
  constexpr int MF = WMSZ / 32;      // A frags per wave (4 or 2)
  constexpr int NBG = BN / 64;       // B staging groups (4 or 2)
  constexpr int LPS = 4 + NBG;       // G2L per thread per K-tile (8 or 6)
  constexpr int RD = MF + 2;         // ds_reads per h-group (6 or 4)

  __shared__ __attribute__((aligned(16))) ushort As[2][BM * 64];
  __shared__ __attribute__((aligned(16))) ushort Bs[2][BN * 64];

  const int tid = threadIdx.x;
  const int lane = tid & 63;
  const int wave = tid >> 6;
  const int z = blockIdx.z;

  // XCD-aware swizzle (nwg is a multiple of 8 in all stages: 256/64/64/256)
  int bx = blockIdx.x, by = blockIdx.y;
  {
    const int gx = gridDim.x;
    const int nwg = gx * gridDim.y;
    int wg = by * gx + bx;
    wg = (wg & 7) * (nwg >> 3) + (wg >> 3);
    bx = wg % gx; by = wg / gx;
  }
  const long m0 = (long)by * BM;
  const long n0 = (long)bx * BN;
  const ushort* Ab = g.A + (long)z * g.asz;
  const ushort* Bb = g.B + (long)z * g.bsz;

  // ---- staging: thread t -> row (t>>3) in each 64-row group, LDS chunk (t&7);
  // global chunk = (ldschunk - row) & 7  (row rotation)
  const int srow = tid >> 3;
  const long skel = (long)((((tid & 7) - srow) & 7) * 8);
  const ushort* ga[4];
  const ushort* gb[NBG];
#pragma unroll
  for (int q = 0; q < 4; ++q) ga[q] = Ab + (m0 + q * 64 + srow) * (long)g.lda + skel;
#pragma unroll
  for (int q = 0; q < NBG; ++q) gb[q] = Bb + (n0 + q * 64 + srow) * (long)g.ldb + skel;

  // ---- fragment read offsets: lane l reads X[r = base + (l&31)][k = 16h + 8*(l>>5) + j]
  // stored chunk = (2h + (l>>5) + r) & 7 ; byte offset = 2*(r*64) + chunk*16
  const int l31 = lane & 31, hb = lane >> 5;
  const int wmi = wave / WN, wni = wave % WN;
  unsigned aoffB[MF]; int arot[MF];
#pragma unroll
  for (int mf = 0; mf < MF; ++mf) {
    const int r = wmi * WMSZ + mf * 32 + l31;
    aoffB[mf] = (unsigned)(r * 128);
    arot[mf] = (r + hb) & 7;
  }
  unsigned boffB[2]; int brot[2];
#pragma unroll
  for (int nf = 0; nf < 2; ++nf) {
    const int r = wni * 64 + nf * 32 + l31;
    boffB[nf] = (unsigned)(r * 128);
    brot[nf] = (r + hb) & 7;
  }

  f32x16 acc[MF][2];
#pragma unroll
  for (int mf = 0; mf < MF; ++mf)
#pragma unroll
    for (int nf = 0; nf < 2; ++nf)
#pragma unroll
      for (int r = 0; r < 16; ++r) acc[mf][nf][r] = 0.f;

  auto STAGEF = [&](int buf, int t) {
    const long ko = (long)t * 64;
#pragma unroll
    for (int q = 0; q < 4; ++q) G2L(ga[q] + ko, &As[buf][q * 4096 + tid * 8]);
#pragma unroll
    for (int q = 0; q < NBG; ++q) G2L(gb[q] + ko, &Bs[buf][q * 4096 + tid * 8]);
  };

  STAGEF(0, 0);            // tile 0 -> buf 0
  STAGEF(1, 1);            // tile 1 -> buf 1   (nt >= 3 in all stages)

  const int nt = g.K >> 6;
  for (int t = 0; t < nt; ++t) {
    const int cur = t & 1;
    // RAW gate: tile t complete; tile t+1's LPS loads stay in flight
    if (t + 1 < nt) asm volatile("s_waitcnt vmcnt(%0)" :: "n"(LPS) : "memory");
    else            asm volatile("s_waitcnt vmcnt(0)" ::: "memory");
    BARRIER();

    const unsigned abase = ldsoff(&As[cur][0]);
    const unsigned bbase = ldsoff(&Bs[cur][0]);
    short8 av[2][MF], bv[2][2];

    // issue RD asm ds_read_b128 for h-group h into slot s (volatile: issue order kept)
#define ISSUE_H(s, h) do { \
  _Pragma("unroll") for (int mf = 0; mf < MF; ++mf) { \
    unsigned o = abase + aoffB[mf] + (unsigned)((((2 * (h) + arot[mf]) & 7) << 4)); \
    asm volatile("ds_read_b128 %0, %1" : "=v"(av[s][mf]) : "v"(o)); \
  } \
  _Pragma("unroll") for (int nf = 0; nf < 2; ++nf) { \
    unsigned o = bbase + boffB[nf] + (unsigned)((((2 * (h) + brot[nf]) & 7) << 4)); \
    asm volatile("ds_read_b128 %0, %1" : "=v"(bv[s][nf]) : "v"(o)); \
  } \
} while (0)
#define MFMA_S(s) do { \
  __builtin_amdgcn_s_setprio(1); \
  _Pragma("unroll") for (int mf = 0; mf < MF; ++mf) \
  _Pragma("unroll") for (int nf = 0; nf < 2; ++nf) \
    acc[mf][nf] = __builtin_amdgcn_mfma_f32_32x32x16_bf16(av[s][mf], bv[s][nf], acc[mf][nf], 0, 0, 0); \
  __builtin_amdgcn_s_setprio(0); \
} while (0)

    ISSUE_H(0, 0);
    ISSUE_H(1, 1);
    LGKMC(RD);          // h0 landed; h1 (RD reads) in flight
    MFMA_S(0);          // MFMA h0 || h1 drain
    ISSUE_H(0, 2);
    LGKMC(RD);          // h1 landed; h2 in flight
    MFMA_S(1);          // MFMA h1 || h2 drain
    ISSUE_H(1, 3);
    LGKMC(RD);          // h2 landed; h3 in flight
    MFMA_S(0);          // MFMA h2 || h3 drain
    LGKMC(0);           // all reads of buf[cur] done (wave-local)
    BARRIER();          // block-wide WAR gate: safe to overwrite buf[cur]
    if (t + 2 < nt) STAGEF(cur, t + 2);
    MFMA_S(1);          // MFMA h3 || G2L issue/flight
#undef ISSUE_H
#undef MFMA_S
  }

  // ---- epilogue: C/D map (m74/m101): col=lane&31, row=(reg&3)+8*(reg>>2)+4*(lane>>5)
  const int cc = l31;
  const int rbase = 4 * hb;
  ushort* Cu = (ushort*)g.C + (long)z * g.csz;
  float* Cf = (float*)g.C;
#pragma unroll
  for (int mf = 0; mf < MF; ++mf) {
#pragma unroll
    for (int nf = 0; nf < 2; ++nf) {
      const long col = n0 + wni * 64 + nf * 32 + cc;
      float bsv = 0.f;
      if (MODE == 0 || MODE == 3) bsv = g.bias[col];
#pragma unroll
      for (int r = 0; r < 16; ++r) {
        const long row = m0 + wmi * WMSZ + mf * 32 + (r & 3) + 8 * (r >> 2) + rbase;
        float v = acc[mf][nf][r] + bsv;
        if (MODE == 3) {
          float* dst = (col < 512) ? (Cf + row * 512 + col) : (g.C2 + row * 512 + (col - 512));
          *dst = v;
        } else {
          Cu[row * (long)g.ldc + col] = f2bf(v);
        }
      }
    }
  }
}

// ---------------- converts ----------------
__global__ void cvt_x6(const float* x0, const float* x1, const float* x2,
                       const float* x3, const float* x4, const float* x5, ushort* X) {
  const long m = blockIdx.y;
  const int c4 = (blockIdx.x * 256 + threadIdx.x) * 4;  // 0..3071
  const int p = c4 >> 9, d = c4 & 511;
  const float* xp;
  switch (p) {
    case 0: xp = x0; break; case 1: xp = x1; break; case 2: xp = x2; break;
    case 3: xp = x3; break; case 4: xp = x4; break; default: xp = x5; break;
  }
  float4 v = *(const float4*)(xp + m * 512 + d);
  ushort4 o; o.x = f2bf(v.x); o.y = f2bf(v.y); o.z = f2bf(v.z); o.w = f2bf(v.w);
  *(ushort4*)(X + m * 3072 + c4) = o;
}

__device__ __forceinline__ int chunk_map(int c) { return (c == 0) ? 0 : (c == 1) ? 2 : (c == 2) ? 4 : 5; }

__global__ void cvt_w4(const float* W, ushort* Wq4) {
  const long r = blockIdx.y;                       // 0..2047
  const int c4 = (blockIdx.x * 256 + threadIdx.x) * 4;
  const long wr = (long)chunk_map((int)(r >> 9)) * 512 + (r & 511);
  float4 v = *(const float4*)(W + wr * 3072 + c4);
  ushort4 o; o.x = f2bf(v.x); o.y = f2bf(v.y); o.z = f2bf(v.z); o.w = f2bf(v.w);
  *(ushort4*)(Wq4 + r * 3072 + c4) = o;
}

__global__ void cvt_wout(const float* W, ushort* Wo) {
  const long r = blockIdx.y;
  const int c4 = threadIdx.x * 4;
  float4 v = *(const float4*)(W + r * 1024 + c4);
  ushort4 o; o.x = f2bf(v.x); o.y = f2bf(v.y); o.z = f2bf(v.z); o.w = f2bf(v.w);
  *(ushort4*)(Wo + r * 1024 + c4) = o;
}

__global__ void mk_bias4(const float* bqkv, float* b4) {
  const int n = blockIdx.x * 256 + threadIdx.x;    // 0..2047
  b4[n] = bqkv[chunk_map(n >> 9) * 512 + (n & 511)];
}

// ---------------- V transpose: Vt_b[n][k] = QKV[b*2048+k][1024+n] ----------------
__global__ void transpose_v(const ushort* QKV, ushort* Vt) {
  __shared__ ushort t[64][65];
  const int tid = threadIdx.x;
  const int k0 = blockIdx.x * 64, n0 = blockIdx.y * 64, b = blockIdx.z;
  const ushort* src = QKV + (long)b * 2048 * 2048 + 1024;
#pragma unroll
  for (int i = 0; i < 16; ++i) {
    int idx = i * 256 + tid; int r = idx >> 6, c = idx & 63;
    t[r][c] = src[(long)(k0 + r) * 2048 + (n0 + c)];
  }
  __syncthreads();
  ushort* dst = Vt + (long)b * 1024 * 2048;
#pragma unroll
  for (int i = 0; i < 16; ++i) {
    int idx = i * 256 + tid; int r = idx >> 6, c = idx & 63;
    dst[(long)(n0 + r) * 2048 + (k0 + c)] = t[c][r];
  }
}

// ---------------- softmax: lane owns one contiguous 64B chunk (32 elems) ----------------
__launch_bounds__(256)
__global__ void softmax_rows(ushort* S, const int* mask) {
  const int lane = threadIdx.x & 63;
  const int wave = threadIdx.x >> 6;
  const long row = (long)blockIdx.x * 4 + wave;            // 0..8191
  const int* m = mask + (row >> 11) * 2048 + lane * 32;
  ushort* s = S + row * 2048 + lane * 32;
  const float scale = 0.04419417382415922f;                // 512^-0.5

  short8 raw[4];
#pragma unroll
  for (int i = 0; i < 4; ++i) raw[i] = *(const short8*)(s + i * 8);
  int4 mi[8];
#pragma unroll
  for (int i = 0; i < 8; ++i) mi[i] = *(const int4*)(m + i * 4);

  float v[32];
  int mk[32];
#pragma unroll
  for (int i = 0; i < 8; ++i) {
    mk[i * 4 + 0] = mi[i].x; mk[i * 4 + 1] = mi[i].y;
    mk[i * 4 + 2] = mi[i].z; mk[i * 4 + 3] = mi[i].w;
  }
#pragma unroll
  for (int i = 0; i < 32; ++i) v[i] = bf2f((ushort)raw[i >> 3][i & 7]) * scale;

  float mx = -INFINITY;
#pragma unroll
  for (int i = 0; i < 32; ++i) if (!mk[i]) mx = fmaxf(mx, v[i]);
#pragma unroll
  for (int off = 32; off; off >>= 1) mx = fmaxf(mx, __shfl_xor(mx, off));

  float sum = 0.f;
#pragma unroll
  for (int i = 0; i < 32; ++i) {
    float e = mk[i] ? 0.f : __expf(v[i] - mx);
    v[i] = e;
    sum += e;
  }
#pragma unroll
  for (int off = 32; off; off >>= 1) sum += __shfl_xor(sum, off);

  float r = 1.f / sum;
  short8 out[4];
#pragma unroll
  for (int i = 0; i < 32; ++i) out[i >> 3][i & 7] = (short)f2bf(v[i] * r);
#pragma unroll
  for (int i = 0; i < 4; ++i) *(short8*)(s + i * 8) = out[i];
}

// ---------------- launcher ----------------
extern "C" void kernel_launch(void* const* d_in, const int* in_sizes, int n_in,
                              void* d_out, int out_size, void* d_ws, size_t ws_size,
                              hipStream_t stream) {
  const float* qr = (const float*)d_in[0];
  const float* qi = (const float*)d_in[1];
  const float* kr = (const float*)d_in[2];
  const float* ki = (const float*)d_in[3];
  const float* vr = (const float*)d_in[4];
  const float* vi = (const float*)d_in[5];
  const int* pm = (const int*)d_in[6];
  const float* Wqkv = (const float*)d_in[7];
  const float* bqkv = (const float*)d_in[8];
  const float* Wout = (const float*)d_in[9];
  const float* bout = (const float*)d_in[10];
  float* out = (float*)d_out;

  // ws layout (bytes):
  char* base = (char*)d_ws;
  ushort* QKV   = (ushort*)(base);                         // 8192x2048 bf16   33,554,432
  ushort* Wq4   = (ushort*)(base + 33554432);              // 2048x3072 bf16   12,582,912
  ushort* Wo    = (ushort*)(base + 46137344);              // 1024x1024 bf16    2,097,152
  float*  b4    = (float*) (base + 48234496);              // 2048 fp32             8,192
  char*   uni   = base + 48242688;
  ushort* Xbf   = (ushort*)(uni);                          // 8192x3072 bf16   50,331,648 (dies after stage1)
  ushort* Vt    = (ushort*)(uni);                          // 4x1024x2048 bf16 16,777,216
  ushort* S     = (ushort*)(uni + 16777216);               // 4x2048x2048 bf16 33,554,432
  ushort* AO    = (ushort*)(uni + 50331648);               // 8192x1024 bf16   16,777,216
  // total 115,351,552 bytes

  // converts
  cvt_x6<<<dim3(3, 8192), 256, 0, stream>>>(qr, qi, kr, ki, vr, vi, Xbf);
  cvt_w4<<<dim3(3, 2048), 256, 0, stream>>>(Wqkv, Wq4);
  cvt_wout<<<dim3(1, 1024), 256, 0, stream>>>(Wout, Wo);
  mk_bias4<<<8, 256, 0, stream>>>(bqkv, b4);

  // stage 1: QKV = Xbf(8192x3072) . Wq4(2048x3072)^T + b4  -> bf16   [grid 256 = 1 block/CU]
  {
    MArgs a{};
    a.A = Xbf; a.lda = 3072; a.asz = 0;
    a.B = Wq4; a.ldb = 3072; a.bsz = 0;
    a.C = QKV; a.ldc = 2048; a.csz = 0;
    a.K = 3072; a.bias = b4;
    mfma_gemm<0, 256><<<dim3(8, 32, 1), 512, 0, stream>>>(a);
  }

  // V transpose (reads QKV cols 1024..2047)
  transpose_v<<<dim3(32, 16, 4), 256, 0, stream>>>(QKV, Vt);

  // stage 2: S_b = Q_b(2048x512) . K_b(2048x512)^T  -> bf16 (raw scores)  [grid 256]
  {
    MArgs a{};
    a.A = QKV;        a.lda = 2048; a.asz = (long)2048 * 2048;
    a.B = QKV + 512;  a.ldb = 2048; a.bsz = (long)2048 * 2048;
    a.C = S;          a.ldc = 2048; a.csz = (long)2048 * 2048;
    a.K = 512;
    mfma_gemm<1, 256><<<dim3(8, 8, 4), 512, 0, stream>>>(a);
  }

  // stage 3: softmax rows in place (scale + mask + exp + norm)
  softmax_rows<<<2048, 256, 0, stream>>>(S, pm);

  // stage 4: AO_b = P_b(2048x2048) . Vt_b(1024x2048)^T  -> bf16   [BN=128, grid 256]
  {
    MArgs a{};
    a.A = S;  a.lda = 2048; a.asz = (long)2048 * 2048;
    a.B = Vt; a.ldb = 2048; a.bsz = (long)1024 * 2048;
    a.C = AO; a.ldc = 1024; a.csz = (long)2048 * 1024;
    a.K = 2048;
    mfma_gemm<2, 128><<<dim3(8, 8, 4), 512, 0, stream>>>(a);
  }

  // stage 5: out = AO(8192x1024) . Wo(1024x1024)^T + bout -> fp32 split   [BN=128, grid 256]
  {
    MArgs a{};
    a.A = AO; a.lda = 1024; a.asz = 0;
    a.B = Wo; a.ldb = 1024; a.bsz = 0;
    a.C = out; a.ldc = 512; a.csz = 0;
    a.C2 = out + (long)8192 * 512;
    a.K = 1024; a.bias = bout;
    mfma_gemm<3, 128><<<dim3(8, 32, 1), 512, 0, stream>>>(a);
  }
}

// Round 6
// 387.912 us; speedup vs baseline: 1.1263x; 1.0101x over previous
//
#include <hip/hip_runtime.h>
#include <cstdint>
#include <cstddef>

typedef unsigned short ushort;
typedef __attribute__((ext_vector_type(8))) short short8;    // 8 x bf16 (4 VGPRs)
typedef __attribute__((ext_vector_type(16))) float f32x16;   // 32x32 accumulator

__device__ __forceinline__ float bf2f(ushort u) {
  union { unsigned u; float f; } c; c.u = ((unsigned)u) << 16; return c.f;
}
__device__ __forceinline__ ushort f2bf(float f) {
  union { float f; unsigned u; } c; c.f = f;
  unsigned u = c.u;
  return (ushort)((u + 0x7fffu + ((u >> 16) & 1u)) >> 16);   // RNE
}

#define G2L(g, l) __builtin_amdgcn_global_load_lds( \
    (const __attribute__((address_space(1))) void*)(g), \
    (__attribute__((address_space(3))) void*)(l), 16, 0, 0)

#define BARRIER() do { asm volatile("" ::: "memory"); __builtin_amdgcn_s_barrier(); asm volatile("" ::: "memory"); } while (0)
// counted LDS wait: oldest (outstanding-N) DS ops complete (DS returns in order).
// rule 18: sched_barrier(0) after, so MFMAs can't hoist above the wait.
#define LGKMC(N) do { asm volatile("s_waitcnt lgkmcnt(%0)" :: "n"(N) : "memory"); __builtin_amdgcn_sched_barrier(0); } while (0)

__device__ __forceinline__ unsigned ldsoff(const void* p) {
  return (unsigned)(unsigned long long)(__attribute__((address_space(3))) const void*)p;
}

// ---------------- MFMA GEMM: C[M,N] = A[M,K] . B[N,K]^T (+bias) ----------------
// 256xBN tile (BN=256 or 128), BK=64, 8 waves (512 thr), double-buffered LDS.
// R6: counted-lgkm pipeline (R5) + CROSS-TILE read prefetch. R5's tile-boundary
// bubbles (~500cyc each: top = vmcnt+barrier+first-read wait with empty LDS queue;
// end = last MFMA group with zero reads outstanding) are closed by moving the
// WAR/STAGE/RAW block BEFORE the final MFMA group and issuing tile t+1's h0 reads
// right after the RAW gate -> h3's MFMAs cover next-tile read drain.
// Per K-tile t (slots: s0 = even h, s1 = odd h; h0(t) issued at end of t-1):
//   ISSUE(s1,h1) -> lgkm(RD)  : h0 landed, h1 in flight
//   MFMA(s0,h0) ; ISSUE(s0,h2) -> lgkm(RD) ; MFMA(s1,h1)
//   ISSUE(s1,h3) -> lgkm(RD) ; MFMA(s0,h2) ; lgkm(0)
//   [t+1<nt:] BARRIER (WAR: buf[cur] fully read block-wide)
//             STAGE(t+2 -> cur) ; vmcnt(t+2<nt ? LPS : 0) ; BARRIER (RAW: t+1 landed)
//             ISSUE(s0, h0 of t+1 from buf[cur^1])
//   MFMA(s1,h3)   <- overlaps next tile's first read drain
// vmcnt never drains to 0 mid-loop (t+2's LPS loads stay in flight across barriers).
// LDS layout: [row][k-chunk], chunk = 8 elems = 16B, row stride 128B.
// Swizzle: global chunk q of row r lives at LDS chunk (q + r) & 7; staging
// pre-rotates the per-lane GLOBAL source (G2L dest stays linear).
// MODE 0: bias fp32, write bf16 / MODE 1,2: write bf16 / MODE 3: bias, fp32 split @512.
struct MArgs {
  const ushort* A; int lda; long asz;
  const ushort* B; int ldb; long bsz;
  void* C; int ldc; long csz;
  int K;
  const float* bias;
  float* C2;
};

template<int MODE, int BN>
__launch_bounds__(512, 2)
__global__ void mfma_gemm(MArgs g) {
  constexpr int BM = 256;
  constexpr int WN = BN / 64;        // waves along N (4 or 2)
  constexpr int WM = 8 / WN;         // waves along M (2 or 4)
  constexpr int WMSZ = BM / WM;      // per-wave M extent (128 or 64)
  constexpr int MF = WMSZ / 32;      // A frags per wave (4 or 2)
  constexpr int NBG = BN / 64;       // B staging groups (4 or 2)
  constexpr int LPS = 4 + NBG;       // G2L per thread per K-tile (8 or 6)
  constexpr int RD = MF + 2;         // ds_reads per h-group (6 or 4)

  __shared__ __attribute__((aligned(16))) ushort As[2][BM * 64];
  __shared__ __attribute__((aligned(16))) ushort Bs[2][BN * 64];

  const int tid = threadIdx.x;
  const int lane = tid & 63;
  const int wave = tid >> 6;
  const int z = blockIdx.z;

  // XCD-aware swizzle (nwg is a multiple of 8 in all stages: 256/64/64/256)
  int bx = blockIdx.x, by = blockIdx.y;
  {
    const int gx = gridDim.x;
    const int nwg = gx * gridDim.y;
    int wg = by * gx + bx;
    wg = (wg & 7) * (nwg >> 3) + (wg >> 3);
    bx = wg % gx; by = wg / gx;
  }
  const long m0 = (long)by * BM;
  const long n0 = (long)bx * BN;
  const ushort* Ab = g.A + (long)z * g.asz;
  const ushort* Bb = g.B + (long)z * g.bsz;

  // ---- staging: thread t -> row (t>>3) in each 64-row group, LDS chunk (t&7);
  // global chunk = (ldschunk - row) & 7  (row rotation)
  const int srow = tid >> 3;
  const long skel = (long)((((tid & 7) - srow) & 7) * 8);
  const ushort* ga[4];
  const ushort* gb[NBG];
#pragma unroll
  for (int q = 0; q < 4; ++q) ga[q] = Ab + (m0 + q * 64 + srow) * (long)g.lda + skel;
#pragma unroll
  for (int q = 0; q < NBG; ++q) gb[q] = Bb + (n0 + q * 64 + srow) * (long)g.ldb + skel;

  // ---- fragment read offsets: lane l reads X[r = base + (l&31)][k = 16h + 8*(l>>5) + j]
  // stored chunk = (2h + (l>>5) + r) & 7 ; byte offset = r*128 + chunk*16
  const int l31 = lane & 31, hb = lane >> 5;
  const int wmi = wave / WN, wni = wave % WN;
  unsigned aoffB[MF]; int arot[MF];
#pragma unroll
  for (int mf = 0; mf < MF; ++mf) {
    const int r = wmi * WMSZ + mf * 32 + l31;
    aoffB[mf] = (unsigned)(r * 128);
    arot[mf] = (r + hb) & 7;
  }
  unsigned boffB[2]; int brot[2];
#pragma unroll
  for (int nf = 0; nf < 2; ++nf) {
    const int r = wni * 64 + nf * 32 + l31;
    boffB[nf] = (unsigned)(r * 128);
    brot[nf] = (r + hb) & 7;
  }

  f32x16 acc[MF][2];
#pragma unroll
  for (int mf = 0; mf < MF; ++mf)
#pragma unroll
    for (int nf = 0; nf < 2; ++nf)
#pragma unroll
      for (int r = 0; r < 16; ++r) acc[mf][nf][r] = 0.f;

  auto STAGEF = [&](int buf, int t) {
    const long ko = (long)t * 64;
#pragma unroll
    for (int q = 0; q < 4; ++q) G2L(ga[q] + ko, &As[buf][q * 4096 + tid * 8]);
#pragma unroll
    for (int q = 0; q < NBG; ++q) G2L(gb[q] + ko, &Bs[buf][q * 4096 + tid * 8]);
  };

  const unsigned abB[2] = { ldsoff(&As[0][0]), ldsoff(&As[1][0]) };
  const unsigned bbB[2] = { ldsoff(&Bs[0][0]), ldsoff(&Bs[1][0]) };
  short8 av[2][MF], bv[2][2];

  // issue RD asm ds_read_b128 for h-group h into slot s from buffers (ab,bb)
#define ISSUE_H(s, h, ab, bb) do { \
  _Pragma("unroll") for (int mf = 0; mf < MF; ++mf) { \
    unsigned o = (ab) + aoffB[mf] + (unsigned)((((2 * (h) + arot[mf]) & 7) << 4)); \
    asm volatile("ds_read_b128 %0, %1" : "=v"(av[s][mf]) : "v"(o)); \
  } \
  _Pragma("unroll") for (int nf = 0; nf < 2; ++nf) { \
    unsigned o = (bb) + boffB[nf] + (unsigned)((((2 * (h) + brot[nf]) & 7) << 4)); \
    asm volatile("ds_read_b128 %0, %1" : "=v"(bv[s][nf]) : "v"(o)); \
  } \
} while (0)
#define MFMA_S(s) do { \
  __builtin_amdgcn_s_setprio(1); \
  _Pragma("unroll") for (int mf = 0; mf < MF; ++mf) \
  _Pragma("unroll") for (int nf = 0; nf < 2; ++nf) \
    acc[mf][nf] = __builtin_amdgcn_mfma_f32_32x32x16_bf16(av[s][mf], bv[s][nf], acc[mf][nf], 0, 0, 0); \
  __builtin_amdgcn_s_setprio(0); \
} while (0)

  STAGEF(0, 0);            // tile 0 -> buf 0
  STAGEF(1, 1);            // tile 1 -> buf 1   (nt >= 3 in all stages)
  asm volatile("s_waitcnt vmcnt(%0)" :: "n"(LPS) : "memory");   // tile 0 landed
  BARRIER();
  ISSUE_H(0, 0, abB[0], bbB[0]);   // h0 of tile 0

  const int nt = g.K >> 6;
  for (int t = 0; t < nt; ++t) {
    const int cur = t & 1;
    const unsigned ab = abB[cur], bb = bbB[cur];

    ISSUE_H(1, 1, ab, bb);
    LGKMC(RD);          // h0 landed (h1 in flight)
    MFMA_S(0);          // h0  || h1 drain
    ISSUE_H(0, 2, ab, bb);
    LGKMC(RD);          // h1 landed (h2 in flight)
    MFMA_S(1);          // h1  || h2 drain
    ISSUE_H(1, 3, ab, bb);
    LGKMC(RD);          // h2 landed (h3 in flight)
    MFMA_S(0);          // h2  || h3 drain
    LGKMC(0);           // h3 landed; all reads of buf[cur] done (wave-local)

    if (t + 1 < nt) {
      BARRIER();                                 // WAR gate: buf[cur] fully read block-wide
      if (t + 2 < nt) {
        STAGEF(cur, t + 2);                      // overwrite buf[cur] with tile t+2
        asm volatile("s_waitcnt vmcnt(%0)" :: "n"(LPS) : "memory");  // t+1 landed, t+2 in flight
      } else {
        asm volatile("s_waitcnt vmcnt(0)" ::: "memory");             // t+1 landed
      }
      BARRIER();                                 // RAW gate block-wide
      ISSUE_H(0, 0, abB[cur ^ 1], bbB[cur ^ 1]); // prefetch h0 of tile t+1
    }
    MFMA_S(1);          // h3  || next tile's h0 drain
  }
#undef ISSUE_H
#undef MFMA_S

  // ---- epilogue: C/D map (m74/m101): col=lane&31, row=(reg&3)+8*(reg>>2)+4*(lane>>5)
  const int cc = l31;
  const int rbase = 4 * hb;
  ushort* Cu = (ushort*)g.C + (long)z * g.csz;
  float* Cf = (float*)g.C;
#pragma unroll
  for (int mf = 0; mf < MF; ++mf) {
#pragma unroll
    for (int nf = 0; nf < 2; ++nf) {
      const long col = n0 + wni * 64 + nf * 32 + cc;
      float bsv = 0.f;
      if (MODE == 0 || MODE == 3) bsv = g.bias[col];
#pragma unroll
      for (int r = 0; r < 16; ++r) {
        const long row = m0 + wmi * WMSZ + mf * 32 + (r & 3) + 8 * (r >> 2) + rbase;
        float v = acc[mf][nf][r] + bsv;
        if (MODE == 3) {
          float* dst = (col < 512) ? (Cf + row * 512 + col) : (g.C2 + row * 512 + (col - 512));
          *dst = v;
        } else {
          Cu[row * (long)g.ldc + col] = f2bf(v);
        }
      }
    }
  }
}

// ---------------- converts ----------------
__global__ void cvt_x6(const float* x0, const float* x1, const float* x2,
                       const float* x3, const float* x4, const float* x5, ushort* X) {
  const long m = blockIdx.y;
  const int c4 = (blockIdx.x * 256 + threadIdx.x) * 4;  // 0..3071
  const int p = c4 >> 9, d = c4 & 511;
  const float* xp;
  switch (p) {
    case 0: xp = x0; break; case 1: xp = x1; break; case 2: xp = x2; break;
    case 3: xp = x3; break; case 4: xp = x4; break; default: xp = x5; break;
  }
  float4 v = *(const float4*)(xp + m * 512 + d);
  ushort4 o; o.x = f2bf(v.x); o.y = f2bf(v.y); o.z = f2bf(v.z); o.w = f2bf(v.w);
  *(ushort4*)(X + m * 3072 + c4) = o;
}

__device__ __forceinline__ int chunk_map(int c) { return (c == 0) ? 0 : (c == 1) ? 2 : (c == 2) ? 4 : 5; }

__global__ void cvt_w4(const float* W, ushort* Wq4) {
  const long r = blockIdx.y;                       // 0..2047
  const int c4 = (blockIdx.x * 256 + threadIdx.x) * 4;
  const long wr = (long)chunk_map((int)(r >> 9)) * 512 + (r & 511);
  float4 v = *(const float4*)(W + wr * 3072 + c4);
  ushort4 o; o.x = f2bf(v.x); o.y = f2bf(v.y); o.z = f2bf(v.z); o.w = f2bf(v.w);
  *(ushort4*)(Wq4 + r * 3072 + c4) = o;
}

__global__ void cvt_wout(const float* W, ushort* Wo) {
  const long r = blockIdx.y;
  const int c4 = threadIdx.x * 4;
  float4 v = *(const float4*)(W + r * 1024 + c4);
  ushort4 o; o.x = f2bf(v.x); o.y = f2bf(v.y); o.z = f2bf(v.z); o.w = f2bf(v.w);
  *(ushort4*)(Wo + r * 1024 + c4) = o;
}

__global__ void mk_bias4(const float* bqkv, float* b4) {
  const int n = blockIdx.x * 256 + threadIdx.x;    // 0..2047
  b4[n] = bqkv[chunk_map(n >> 9) * 512 + (n & 511)];
}

// ---------------- V transpose: Vt_b[n][k] = QKV[b*2048+k][1024+n] ----------------
// R6: 16B/lane global loads AND stores (old version was 2B/lane, ~40us for 33MB).
// LDS tile [64 n][68 k] ushort (136B row stride = 34 banks = 2 mod 32: spread).
// Scalar LDS ops only (8KB/block of LDS traffic - negligible).
__global__ void transpose_v(const ushort* QKV, ushort* Vt) {
  __shared__ ushort t2[64][68];
  const int tid = threadIdx.x;
  const int k0 = blockIdx.x * 64, n0 = blockIdx.y * 64, b = blockIdx.z;
  const ushort* src = QKV + (long)b * 2048 * 2048 + 1024;
#pragma unroll
  for (int i = 0; i < 2; ++i) {
    const int slot = i * 256 + tid;                // 0..511
    const int kr = slot >> 3, nc = slot & 7;
    short8 v = *(const short8*)(src + (long)(k0 + kr) * 2048 + (n0 + nc * 8));
#pragma unroll
    for (int j = 0; j < 8; ++j) t2[nc * 8 + j][kr] = (ushort)v[j];
  }
  __syncthreads();
  ushort* dst = Vt + (long)b * 1024 * 2048;
#pragma unroll
  for (int i = 0; i < 2; ++i) {
    const int slot = i * 256 + tid;
    const int nr = slot >> 3, kc = slot & 7;
    short8 v;
#pragma unroll
    for (int j = 0; j < 8; ++j) v[j] = (short)t2[nr][kc * 8 + j];
    *(short8*)(dst + (long)(n0 + nr) * 2048 + (k0 + kc * 8)) = v;
  }
}

// ---------------- softmax: lane owns one contiguous 64B chunk (32 elems) ----------------
__launch_bounds__(256)
__global__ void softmax_rows(ushort* S, const int* mask) {
  const int lane = threadIdx.x & 63;
  const int wave = threadIdx.x >> 6;
  const long row = (long)blockIdx.x * 4 + wave;            // 0..8191
  const int* m = mask + (row >> 11) * 2048 + lane * 32;
  ushort* s = S + row * 2048 + lane * 32;
  const float scale = 0.04419417382415922f;                // 512^-0.5

  short8 raw[4];
#pragma unroll
  for (int i = 0; i < 4; ++i) raw[i] = *(const short8*)(s + i * 8);
  int4 mi[8];
#pragma unroll
  for (int i = 0; i < 8; ++i) mi[i] = *(const int4*)(m + i * 4);

  float v[32];
  int mk[32];
#pragma unroll
  for (int i = 0; i < 8; ++i) {
    mk[i * 4 + 0] = mi[i].x; mk[i * 4 + 1] = mi[i].y;
    mk[i * 4 + 2] = mi[i].z; mk[i * 4 + 3] = mi[i].w;
  }
#pragma unroll
  for (int i = 0; i < 32; ++i) v[i] = bf2f((ushort)raw[i >> 3][i & 7]) * scale;

  float mx = -INFINITY;
#pragma unroll
  for (int i = 0; i < 32; ++i) if (!mk[i]) mx = fmaxf(mx, v[i]);
#pragma unroll
  for (int off = 32; off; off >>= 1) mx = fmaxf(mx, __shfl_xor(mx, off));

  float sum = 0.f;
#pragma unroll
  for (int i = 0; i < 32; ++i) {
    float e = mk[i] ? 0.f : __expf(v[i] - mx);
    v[i] = e;
    sum += e;
  }
#pragma unroll
  for (int off = 32; off; off >>= 1) sum += __shfl_xor(sum, off);

  float r = 1.f / sum;
  short8 out[4];
#pragma unroll
  for (int i = 0; i < 32; ++i) out[i >> 3][i & 7] = (short)f2bf(v[i] * r);
#pragma unroll
  for (int i = 0; i < 4; ++i) *(short8*)(s + i * 8) = out[i];
}

// ---------------- launcher ----------------
extern "C" void kernel_launch(void* const* d_in, const int* in_sizes, int n_in,
                              void* d_out, int out_size, void* d_ws, size_t ws_size,
                              hipStream_t stream) {
  const float* qr = (const float*)d_in[0];
  const float* qi = (const float*)d_in[1];
  const float* kr = (const float*)d_in[2];
  const float* ki = (const float*)d_in[3];
  const float* vr = (const float*)d_in[4];
  const float* vi = (const float*)d_in[5];
  const int* pm = (const int*)d_in[6];
  const float* Wqkv = (const float*)d_in[7];
  const float* bqkv = (const float*)d_in[8];
  const float* Wout = (const float*)d_in[9];
  const float* bout = (const float*)d_in[10];
  float* out = (float*)d_out;

  // ws layout (bytes):
  char* base = (char*)d_ws;
  ushort* QKV   = (ushort*)(base);                         // 8192x2048 bf16   33,554,432
  ushort* Wq4   = (ushort*)(base + 33554432);              // 2048x3072 bf16   12,582,912
  ushort* Wo    = (ushort*)(base + 46137344);              // 1024x1024 bf16    2,097,152
  float*  b4    = (float*) (base + 48234496);              // 2048 fp32             8,192
  char*   uni   = base + 48242688;
  ushort* Xbf   = (ushort*)(uni);                          // 8192x3072 bf16   50,331,648 (dies after stage1)
  ushort* Vt    = (ushort*)(uni);                          // 4x1024x2048 bf16 16,777,216
  ushort* S     = (ushort*)(uni + 16777216);               // 4x2048x2048 bf16 33,554,432
  ushort* AO    = (ushort*)(uni + 50331648);               // 8192x1024 bf16   16,777,216
  // total 115,351,552 bytes

  // converts
  cvt_x6<<<dim3(3, 8192), 256, 0, stream>>>(qr, qi, kr, ki, vr, vi, Xbf);
  cvt_w4<<<dim3(3, 2048), 256, 0, stream>>>(Wqkv, Wq4);
  cvt_wout<<<dim3(1, 1024), 256, 0, stream>>>(Wout, Wo);
  mk_bias4<<<8, 256, 0, stream>>>(bqkv, b4);

  // stage 1: QKV = Xbf(8192x3072) . Wq4(2048x3072)^T + b4  -> bf16   [grid 256 = 1 block/CU]
  {
    MArgs a{};
    a.A = Xbf; a.lda = 3072; a.asz = 0;
    a.B = Wq4; a.ldb = 3072; a.bsz = 0;
    a.C = QKV; a.ldc = 2048; a.csz = 0;
    a.K = 3072; a.bias = b4;
    mfma_gemm<0, 256><<<dim3(8, 32, 1), 512, 0, stream>>>(a);
  }

  // V transpose (reads QKV cols 1024..2047)
  transpose_v<<<dim3(32, 16, 4), 256, 0, stream>>>(QKV, Vt);

  // stage 2: S_b = Q_b(2048x512) . K_b(2048x512)^T  -> bf16 (raw scores)  [grid 256]
  {
    MArgs a{};
    a.A = QKV;        a.lda = 2048; a.asz = (long)2048 * 2048;
    a.B = QKV + 512;  a.ldb = 2048; a.bsz = (long)2048 * 2048;
    a.C = S;          a.ldc = 2048; a.csz = (long)2048 * 2048;
    a.K = 512;
    mfma_gemm<1, 256><<<dim3(8, 8, 4), 512, 0, stream>>>(a);
  }

  // stage 3: softmax rows in place (scale + mask + exp + norm)
  softmax_rows<<<2048, 256, 0, stream>>>(S, pm);

  // stage 4: AO_b = P_b(2048x2048) . Vt_b(1024x2048)^T  -> bf16   [BN=128, grid 256]
  {
    MArgs a{};
    a.A = S;  a.lda = 2048; a.asz = (long)2048 * 2048;
    a.B = Vt; a.ldb = 2048; a.bsz = (long)1024 * 2048;
    a.C = AO; a.ldc = 1024; a.csz = (long)2048 * 1024;
    a.K = 2048;
    mfma_gemm<2, 128><<<dim3(8, 8, 4), 512, 0, stream>>>(a);
  }

  // stage 5: out = AO(8192x1024) . Wo(1024x1024)^T + bout -> fp32 split   [BN=128, grid 256]
  {
    MArgs a{};
    a.A = AO; a.lda = 1024; a.asz = 0;
    a.B = Wo; a.ldb = 1024; a.bsz = 0;
    a.C = out; a.ldc = 512; a.csz = 0;
    a.C2 = out + (long)8192 * 512;
    a.K = 1024; a.bias = bout;
    mfma_gemm<3, 128><<<dim3(8, 32, 1), 512, 0, stream>>>(a);
  }
}